// Round 9
// baseline (3040.643 us; speedup 1.0000x reference)
//
#include <hip/hip_runtime.h>
#include <hip/hip_bf16.h>

#define H 2048
#define FDIM 1408
#define NE 64
#define CAP 512
#define NTOK 2048
#define FSH 2816

typedef float  f32x4  __attribute__((ext_vector_type(4)));
typedef float  f32x2  __attribute__((ext_vector_type(2)));
typedef short  s16x8  __attribute__((ext_vector_type(8)));
typedef unsigned short u16;
typedef u16    u16x4v __attribute__((ext_vector_type(4)));

__device__ __forceinline__ u16 f2bf(float f) {
    union { float f; unsigned u; } v; v.f = f;
    unsigned u = v.u;
    u += 0x7fffu + ((u >> 16) & 1u);
    return (u16)(u >> 16);
}
__device__ __forceinline__ float bf2f(u16 b) {
    union { unsigned u; float f; } v; v.u = ((unsigned)b) << 16;
    return v.f;
}

// barrier that does NOT drain vmcnt (global loads stay in flight)
#define BAR() do { asm volatile("s_waitcnt lgkmcnt(0)" ::: "memory"); \
                   __builtin_amdgcn_s_barrier(); } while (0)
#define SCHED_FENCE() __builtin_amdgcn_sched_barrier(0)

// ---------------- x fp32 -> bf16 once ----------------
__global__ __launch_bounds__(256) void xcvt(const float* __restrict__ x, u16* __restrict__ xb) {
    int i = blockIdx.x * 256 + threadIdx.x;
    const float4 a = ((const float4*)x)[2 * i];
    const float4 b = ((const float4*)x)[2 * i + 1];
    u16 v[8] = { f2bf(a.x), f2bf(a.y), f2bf(a.z), f2bf(a.w),
                 f2bf(b.x), f2bf(b.y), f2bf(b.z), f2bf(b.w) };
    *(s16x8*)(xb + (size_t)i * 8) = *(s16x8*)v;
}

// ---------------- init ----------------
__global__ void init_cnt(int* __restrict__ c) { c[threadIdx.x] = 0; }

// ---------------- gate: logits -> softmax -> top6 -> slot assign ----------------
__global__ __launch_bounds__(64) void gate_topk(
    const float* __restrict__ xg, const float* __restrict__ gw,
    int* __restrict__ cnt, int* __restrict__ tok_of,
    int* __restrict__ slot_enc, float* __restrict__ tw)
{
    const int t = blockIdx.x;
    const int lane = threadIdx.x;
    __shared__ float4 xs[512];
    const float4* xr = (const float4*)(xg + (size_t)t * H);
    #pragma unroll
    for (int i = 0; i < 8; ++i) xs[i * 64 + lane] = xr[i * 64 + lane];
    __syncthreads();

    const float4* gr = (const float4*)(gw + (size_t)lane * H);
    float acc = 0.f;
    #pragma unroll 4
    for (int i = 0; i < 512; ++i) {
        float4 a = xs[i], b = gr[i];
        acc += a.x * b.x + a.y * b.y + a.z * b.z + a.w * b.w;
    }
    float m = acc;
    #pragma unroll
    for (int off = 32; off; off >>= 1) m = fmaxf(m, __shfl_xor(m, off));
    float p = __expf(acc - m);
    float s = p;
    #pragma unroll
    for (int off = 32; off; off >>= 1) s += __shfl_xor(s, off);
    p = p / s;

    float myw = 0.f; int mye = 0;
    float v = p;
    for (int k = 0; k < 6; ++k) {
        float bv = v; int bi = lane;
        #pragma unroll
        for (int off = 32; off; off >>= 1) {
            float ov = __shfl_xor(bv, off);
            int   oi = __shfl_xor(bi, off);
            if (ov > bv || (ov == bv && oi < bi)) { bv = ov; bi = oi; }
        }
        if (lane == k)  { myw = bv; mye = bi; }
        if (lane == bi) v = -1.f;
    }
    if (lane < 6) {
        int slot = atomicAdd(&cnt[mye], 1);
        int enc = -1;
        if (slot < CAP) { tok_of[mye * CAP + slot] = t; enc = mye * CAP + slot; }
        slot_enc[t * 6 + lane] = enc;
        tw[t * 6 + lane] = myw;               // SCALE == 1.0
    }
}

// ---------------- fused gate+up grouped GEMM + SiLU ----------------
// BM=256, BN=32/mat, BK=64. A: per-wave direct global->reg (MFMA layout),
// depth-2 static sets, never drained at barriers. B: single-buffered LDS,
// R6/R7-proven two-barrier bracket: COMPUTE -> BAR -> STOREB+LOADB -> BAR.
template<bool ROUTED>
__global__ __launch_bounds__(256, 3) void dual_gemm(
    const u16* __restrict__ xbf, const int* __restrict__ tok_of,
    const int* __restrict__ cnt_arr, const float* __restrict__ wg,
    const float* __restrict__ wu, u16* __restrict__ act, int Fd)
{
    __shared__ u16 Bgs[8][32][8];         // 4 KB  (k8-blocked, single buf)
    __shared__ u16 Bus[8][32][8];         // 4 KB

    int e = 0, cnt, m0, f0;
    if constexpr (ROUTED) {
        e = blockIdx.z;
        cnt = cnt_arr[e]; cnt = cnt < CAP ? cnt : CAP;
        f0 = blockIdx.x * 32; m0 = blockIdx.y * 256;
        if (m0 >= cnt) return;
    } else {
        cnt = NTOK;
        m0 = blockIdx.x * 256; f0 = blockIdx.y * 32;
    }

    const float* wg_e = wg;
    const float* wu_e = wu;
    u16* act_e = act;
    if constexpr (ROUTED) {
        wg_e += (size_t)e * H * Fd;
        wu_e += (size_t)e * H * Fd;
        act_e += (size_t)e * CAP * Fd;
    }

    const int tid = threadIdx.x;
    const int lane = tid & 63;
    const int wv = tid >> 6;
    const int NT = H / 64;                // 32, even

    // ---- A: per-lane row pointers in MFMA fragment layout ----
    const int kg = (lane >> 4) * 8;       // k-granule within a 32-k block
    const u16* ap[4];
    #pragma unroll
    for (int mi = 0; mi < 4; ++mi) {
        int srow = m0 + wv * 64 + mi * 16 + (lane & 15);
        if constexpr (ROUTED) {
            const int* tok = tok_of + e * CAP;
            ap[mi] = xbf + (size_t)tok[srow < cnt ? srow : 0] * H + kg;
        } else {
            ap[mi] = xbf + (size_t)srow * H + kg;
        }
    }
    // ---- B geometry ----
    const int mat = tid >> 7;
    const int bb = tid & 127;
    const float* bsrc;
    int n2 = 0, kq = 0, dr = 0, dcq = 0;
    if constexpr (ROUTED) {
        n2 = bb & 15; kq = bb >> 3 & 0xF; kq = bb >> 4;   // 16x2 cols, 8 k-quads
        bsrc = (mat ? wu_e : wg_e) + (size_t)(kq * 4) * Fd + f0 + n2 * 2;
    } else {
        dr = bb >> 2; dcq = bb & 3;                        // 32 rows, 4x16 k
        bsrc = (mat ? wu_e : wg_e) + (size_t)(f0 + dr) * H + dcq * 16;
    }

    f32x4 accg[4][2], accu[4][2];
    const f32x4 zero4 = {0.f, 0.f, 0.f, 0.f};
    #pragma unroll
    for (int i = 0; i < 4; ++i)
        #pragma unroll
        for (int j = 0; j < 2; ++j) { accg[i][j] = zero4; accu[i][j] = zero4; }

    s16x8 aA0[8], aA1[8];                 // [kk*4 + mi]
    f32x2 bR2[8];
    f32x4 bR4[4];

    auto LOADA = [&](int kt, s16x8 (&a)[8]) {
        #pragma unroll
        for (int kk = 0; kk < 2; ++kk)
            #pragma unroll
            for (int mi = 0; mi < 4; ++mi)
                a[kk * 4 + mi] = *(const s16x8*)(ap[mi] + kt * 64 + kk * 32);
    };
    auto LOADB = [&](int kt) {
        if constexpr (ROUTED) {
            #pragma unroll
            for (int j = 0; j < 4; ++j) {
                bR2[j]     = *(const f32x2*)(bsrc + ((size_t)kt * 64 + j) * Fd);
                bR2[4 + j] = *(const f32x2*)(bsrc + ((size_t)kt * 64 + 32 + j) * Fd);
            }
        } else {
            #pragma unroll
            for (int q = 0; q < 4; ++q)
                bR4[q] = *(const f32x4*)(bsrc + kt * 64 + q * 4);
        }
    };
    auto STOREB = [&]() {
        u16* Bdst = mat ? &Bus[0][0][0] : &Bgs[0][0][0];
        if constexpr (ROUTED) {
            #pragma unroll
            for (int c = 0; c < 2; ++c) {
                u16x4v v0, v1;
                #pragma unroll
                for (int j = 0; j < 4; ++j) { v0[j] = f2bf(bR2[j][c]); v1[j] = f2bf(bR2[4 + j][c]); }
                *(u16x4v*)&Bdst[((kq >> 1)) * 256 + (n2 * 2 + c) * 8 + (kq & 1) * 4] = v0;
                *(u16x4v*)&Bdst[(4 + (kq >> 1)) * 256 + (n2 * 2 + c) * 8 + (kq & 1) * 4] = v1;
            }
        } else {
            #pragma unroll
            for (int q = 0; q < 4; ++q) {
                u16x4v v;
                v[0] = f2bf(bR4[q][0]); v[1] = f2bf(bR4[q][1]);
                v[2] = f2bf(bR4[q][2]); v[3] = f2bf(bR4[q][3]);
                *(u16x4v*)&Bdst[(dcq * 2 + (q >> 1)) * 256 + dr * 8 + (q & 1) * 4] = v;
            }
        }
    };
    auto COMPUTE = [&](const s16x8 (&a)[8]) {
        __builtin_amdgcn_s_setprio(1);
        const int j8 = lane >> 4;
        #pragma unroll
        for (int kk = 0; kk < 2; ++kk) {
            const int g = kk * 4 + j8;
            s16x8 bg[2], bu[2];
            #pragma unroll
            for (int ni = 0; ni < 2; ++ni) {
                int c = ni * 16 + (lane & 15);
                bg[ni] = *(const s16x8*)&Bgs[g][c][0];
                bu[ni] = *(const s16x8*)&Bus[g][c][0];
            }
            #pragma unroll
            for (int mi = 0; mi < 4; ++mi)
                #pragma unroll
                for (int ni = 0; ni < 2; ++ni) {
                    accg[mi][ni] = __builtin_amdgcn_mfma_f32_16x16x32_bf16(a[kk * 4 + mi], bg[ni], accg[mi][ni], 0, 0, 0);
                    accu[mi][ni] = __builtin_amdgcn_mfma_f32_16x16x32_bf16(a[kk * 4 + mi], bu[ni], accu[mi][ni], 0, 0, 0);
                }
        }
        __builtin_amdgcn_s_setprio(0);
    };

    // ---- prologue: B(0) staged+published; A(0) in flight ----
    LOADA(0, aA0);
    LOADB(0);
    STOREB();
    LOADB(1);
    BAR(); SCHED_FENCE();

    for (int kt = 0; kt < NT; kt += 2) {
        // phase A: tile kt (aA0, Bs=B(kt))
        if (kt + 1 < NT) LOADA(kt + 1, aA1);
        SCHED_FENCE();
        COMPUTE(aA0);
        BAR();                              // readers of Bs done
        if (kt + 1 < NT) {
            STOREB();                       // B(kt+1) -> Bs
            if (kt + 2 < NT) LOADB(kt + 2);
        }
        SCHED_FENCE();
        BAR(); SCHED_FENCE();               // B(kt+1) published
        // phase B: tile kt+1 (aA1) — NT even => always valid
        if (kt + 2 < NT) LOADA(kt + 2, aA0);
        SCHED_FENCE();
        COMPUTE(aA1);
        BAR();
        if (kt + 2 < NT) {
            STOREB();                       // B(kt+2) -> Bs
            if (kt + 3 < NT) LOADB(kt + 3);
        }
        SCHED_FENCE();
        BAR(); SCHED_FENCE();
    }

    // ---- epilogue: silu(g)*u -> bf16 act (linear layout) ----
    #pragma unroll
    for (int mi = 0; mi < 4; ++mi)
        #pragma unroll
        for (int ni = 0; ni < 2; ++ni)
            #pragma unroll
            for (int r = 0; r < 4; ++r) {
                int srow = m0 + wv * 64 + mi * 16 + (lane >> 4) * 4 + r;
                if (srow < cnt) {
                    int fc = f0 + ni * 16 + (lane & 15);
                    float g = accg[mi][ni][r], u = accu[mi][ni][r];
                    float aa = (g / (1.f + __expf(-g))) * u;
                    act_e[(size_t)srow * Fd + fc] = f2bf(aa);
                }
            }
}

// ---------------- down-proj grouped GEMM ----------------
// BM=256, BN=64, BK=64. Same discipline as dual_gemm.
template<bool ROUTED>
__global__ __launch_bounds__(256, 2) void down_gemm(
    const u16* __restrict__ actA, const float* __restrict__ wdn,
    void* __restrict__ outp, const int* __restrict__ cnt_arr, int Kd)
{
    __shared__ u16 Bs[8][64][8];          // 8 KB (single buf)

    int e = 0, cnt, m0, n0;
    if constexpr (ROUTED) {
        e = blockIdx.z;
        cnt = cnt_arr[e]; cnt = cnt < CAP ? cnt : CAP;
        n0 = blockIdx.x * 64; m0 = blockIdx.y * 256;
        if (m0 >= cnt) return;
    } else {
        cnt = NTOK;
        m0 = blockIdx.x * 256; n0 = blockIdx.y * 64;
    }

    const u16* A_e = actA;
    const float* B_e = wdn;
    if constexpr (ROUTED) {
        A_e += (size_t)e * CAP * Kd;
        B_e += (size_t)e * Kd * H;
    }
    const int NT = Kd / 64;               // 22 or 44, even
    const int tid = threadIdx.x, lane = tid & 63, wv = tid >> 6;

    const int kg = (lane >> 4) * 8;
    const u16* ap[4];
    #pragma unroll
    for (int mi = 0; mi < 4; ++mi) {
        int srow = m0 + wv * 64 + mi * 16 + (lane & 15);
        ap[mi] = A_e + (size_t)srow * Kd + kg;
    }
    const float* bsrc;
    int n2 = 0, kq = 0, dr = 0, dcq = 0;
    if constexpr (ROUTED) {
        n2 = tid & 31; kq = tid >> 5;              // 32x2 cols, 8 k-quads
        bsrc = B_e + (size_t)(kq * 4) * H + n0 + n2 * 2;
    } else {
        dr = tid >> 2; dcq = tid & 3;              // 64 rows, 4x16 k
        bsrc = B_e + (size_t)(n0 + dr) * FSH + dcq * 16;
    }

    f32x4 acc[4][4];
    const f32x4 zero4 = {0.f, 0.f, 0.f, 0.f};
    #pragma unroll
    for (int i = 0; i < 4; ++i)
        #pragma unroll
        for (int j = 0; j < 4; ++j) acc[i][j] = zero4;

    s16x8 aA0[8], aA1[8];
    f32x2 bR2[8];
    f32x4 bR4[4];

    auto LOADA = [&](int kt, s16x8 (&a)[8]) {
        #pragma unroll
        for (int kk = 0; kk < 2; ++kk)
            #pragma unroll
            for (int mi = 0; mi < 4; ++mi)
                a[kk * 4 + mi] = *(const s16x8*)(ap[mi] + kt * 64 + kk * 32);
    };
    auto LOADB = [&](int kt) {
        if constexpr (ROUTED) {
            #pragma unroll
            for (int j = 0; j < 4; ++j) {
                bR2[j]     = *(const f32x2*)(bsrc + ((size_t)kt * 64 + j) * H);
                bR2[4 + j] = *(const f32x2*)(bsrc + ((size_t)kt * 64 + 32 + j) * H);
            }
        } else {
            #pragma unroll
            for (int q = 0; q < 4; ++q)
                bR4[q] = *(const f32x4*)(bsrc + kt * 64 + q * 4);
        }
    };
    auto STOREB = [&]() {
        if constexpr (ROUTED) {
            #pragma unroll
            for (int c = 0; c < 2; ++c) {
                u16x4v v0, v1;
                #pragma unroll
                for (int j = 0; j < 4; ++j) { v0[j] = f2bf(bR2[j][c]); v1[j] = f2bf(bR2[4 + j][c]); }
                *(u16x4v*)&Bs[(kq >> 1)][n2 * 2 + c][(kq & 1) * 4] = v0;
                *(u16x4v*)&Bs[4 + (kq >> 1)][n2 * 2 + c][(kq & 1) * 4] = v1;
            }
        } else {
            #pragma unroll
            for (int q = 0; q < 4; ++q) {
                u16x4v v;
                v[0] = f2bf(bR4[q][0]); v[1] = f2bf(bR4[q][1]);
                v[2] = f2bf(bR4[q][2]); v[3] = f2bf(bR4[q][3]);
                *(u16x4v*)&Bs[dcq * 2 + (q >> 1)][dr][(q & 1) * 4] = v;
            }
        }
    };
    auto COMPUTE = [&](const s16x8 (&a)[8]) {
        __builtin_amdgcn_s_setprio(1);
        const int j8 = lane >> 4;
        #pragma unroll
        for (int kk = 0; kk < 2; ++kk) {
            const int g = kk * 4 + j8;
            s16x8 bf[4];
            #pragma unroll
            for (int ni = 0; ni < 4; ++ni)
                bf[ni] = *(const s16x8*)&Bs[g][ni * 16 + (lane & 15)][0];
            #pragma unroll
            for (int mi = 0; mi < 4; ++mi)
                #pragma unroll
                for (int ni = 0; ni < 4; ++ni)
                    acc[mi][ni] = __builtin_amdgcn_mfma_f32_16x16x32_bf16(a[kk * 4 + mi], bf[ni], acc[mi][ni], 0, 0, 0);
        }
        __builtin_amdgcn_s_setprio(0);
    };

    LOADA(0, aA0);
    LOADB(0);
    STOREB();
    LOADB(1);
    BAR(); SCHED_FENCE();

    for (int kt = 0; kt < NT; kt += 2) {
        if (kt + 1 < NT) LOADA(kt + 1, aA1);
        SCHED_FENCE();
        COMPUTE(aA0);
        BAR();
        if (kt + 1 < NT) {
            STOREB();
            if (kt + 2 < NT) LOADB(kt + 2);
        }
        SCHED_FENCE();
        BAR(); SCHED_FENCE();
        if (kt + 2 < NT) LOADA(kt + 2, aA0);
        SCHED_FENCE();
        COMPUTE(aA1);
        BAR();
        if (kt + 2 < NT) {
            STOREB();
            if (kt + 3 < NT) LOADB(kt + 3);
        }
        SCHED_FENCE();
        BAR(); SCHED_FENCE();
    }

    #pragma unroll
    for (int mi = 0; mi < 4; ++mi)
        #pragma unroll
        for (int ni = 0; ni < 4; ++ni)
            #pragma unroll
            for (int r = 0; r < 4; ++r) {
                int srow = m0 + wv * 64 + mi * 16 + (lane >> 4) * 4 + r;
                if (srow < cnt) {
                    int col = n0 + ni * 16 + (lane & 15);
                    float vv = acc[mi][ni][r];
                    if constexpr (ROUTED)
                        ((u16*)outp)[(size_t)e * CAP * H + (size_t)srow * H + col] = f2bf(vv);
                    else
                        ((float*)outp)[(size_t)srow * H + col] = vv;
                }
            }
}

// ---------------- combine: y += sum_k w_k * d[enc_k] ----------------
__global__ __launch_bounds__(256) void combine(
    float* __restrict__ y, const u16* __restrict__ d,
    const int* __restrict__ slot_enc, const float* __restrict__ tw)
{
    const int t = blockIdx.x, tid = threadIdx.x;
    int enc[6]; float w[6];
    #pragma unroll
    for (int k = 0; k < 6; ++k) {
        enc[k] = slot_enc[t * 6 + k];
        w[k] = tw[t * 6 + k];
    }
    float4* yrow = (float4*)(y + (size_t)t * H);
    #pragma unroll
    for (int it = 0; it < 2; ++it) {
        int h4 = it * 256 + tid;
        float4 acc = yrow[h4];
        #pragma unroll
        for (int k = 0; k < 6; ++k) {
            if (enc[k] >= 0) {
                ushort4 dv = ((const ushort4*)(d + (size_t)enc[k] * H))[h4];
                acc.x += w[k] * bf2f(dv.x);
                acc.y += w[k] * bf2f(dv.y);
                acc.z += w[k] * bf2f(dv.z);
                acc.w += w[k] * bf2f(dv.w);
            }
        }
        yrow[h4] = acc;
    }
}

extern "C" void kernel_launch(void* const* d_in, const int* in_sizes, int n_in,
                              void* d_out, int out_size, void* d_ws, size_t ws_size,
                              hipStream_t stream) {
    const float* x       = (const float*)d_in[0];
    const float* gw      = (const float*)d_in[1];
    const float* w_gate  = (const float*)d_in[2];
    const float* w_up    = (const float*)d_in[3];
    const float* w_down  = (const float*)d_in[4];
    const float* sh_gate = (const float*)d_in[5];
    const float* sh_up   = (const float*)d_in[6];
    const float* sh_down = (const float*)d_in[7];
    float* y = (float*)d_out;

    char* wsb = (char*)d_ws;
    int*   cnt      = (int*)(wsb + 0);                       // 64 ints
    int*   tok_of   = (int*)(wsb + 512);                     // 64*512 ints
    int*   slot_enc = (int*)(wsb + 512 + 131072);            // 2048*6 ints
    float* tw       = (float*)(wsb + 512 + 131072 + 49152);  // 2048*6 floats
    u16*   act      = (u16*)(wsb + 230144);                  // 64*512*1408 bf16
    u16*   actsh    = (u16*)(wsb + 230144 + 92274688);       // 2048*2816 bf16
    u16*   dbuf     = (u16*)(wsb + 230144 + 92274688 + 11534336); // 64*512*2048 bf16
    u16*   xbf      = dbuf;  // alias: xbf (8MB) dead before down_gemm writes dbuf

    init_cnt<<<1, 64, 0, stream>>>(cnt);
    xcvt<<<NTOK * H / 8 / 256, 256, 0, stream>>>(x, xbf);
    gate_topk<<<NTOK, 64, 0, stream>>>(x, gw, cnt, tok_of, slot_enc, tw);
    dual_gemm<true><<<dim3(FDIM / 32, 2, NE), 256, 0, stream>>>(
        xbf, tok_of, cnt, w_gate, w_up, act, FDIM);
    dual_gemm<false><<<dim3(NTOK / 256, FSH / 32, 1), 256, 0, stream>>>(
        xbf, nullptr, nullptr, sh_gate, sh_up, actsh, FSH);
    down_gemm<true><<<dim3(H / 64, 2, NE), 256, 0, stream>>>(
        act, w_down, (void*)dbuf, cnt, FDIM);
    down_gemm<false><<<dim3(NTOK / 256, H / 64, 1), 256, 0, stream>>>(
        actsh, sh_down, (void*)y, nullptr, FSH);
    combine<<<NTOK, 256, 0, stream>>>(y, dbuf, slot_enc, tw);
}

// Round 10
// 2331.359 us; speedup vs baseline: 1.3042x; 1.3042x over previous
//
#include <hip/hip_runtime.h>
#include <hip/hip_bf16.h>

#define H 2048
#define FDIM 1408
#define NE 64
#define CAP 512
#define NTOK 2048
#define FSH 2816

typedef float  f32x4  __attribute__((ext_vector_type(4)));
typedef short  s16x8  __attribute__((ext_vector_type(8)));
typedef unsigned short u16;
typedef u16    u16x4v __attribute__((ext_vector_type(4)));

__device__ __forceinline__ u16 f2bf(float f) {
    union { float f; unsigned u; } v; v.f = f;
    unsigned u = v.u;
    u += 0x7fffu + ((u >> 16) & 1u);
    return (u16)(u >> 16);
}
__device__ __forceinline__ float bf2f(u16 b) {
    union { unsigned u; float f; } v; v.u = ((unsigned)b) << 16;
    return v.f;
}
// element-granular XOR swizzle (8-elem = 16B granules) within 64-elem rows
__device__ __forceinline__ int swze(int row) {
    return (((row & 7) ^ ((row >> 3) & 7)) << 3);
}
__device__ __forceinline__ void wr4(u16* dst, float a, float b, float c, float d) {
    u16x4v v; v[0] = f2bf(a); v[1] = f2bf(b); v[2] = f2bf(c); v[3] = f2bf(d);
    *(u16x4v*)dst = v;
}

// barrier that does NOT drain vmcnt (global loads stay in flight)
#define BAR() do { asm volatile("s_waitcnt lgkmcnt(0)" ::: "memory"); \
                   __builtin_amdgcn_s_barrier(); } while (0)
#define SCHED_FENCE() __builtin_amdgcn_sched_barrier(0)

// ---------------- x fp32 -> bf16 once ----------------
__global__ __launch_bounds__(256) void xcvt(const float* __restrict__ x, u16* __restrict__ xb) {
    int i = blockIdx.x * 256 + threadIdx.x;
    const float4 a = ((const float4*)x)[2 * i];
    const float4 b = ((const float4*)x)[2 * i + 1];
    u16 v[8] = { f2bf(a.x), f2bf(a.y), f2bf(a.z), f2bf(a.w),
                 f2bf(b.x), f2bf(b.y), f2bf(b.z), f2bf(b.w) };
    *(s16x8*)(xb + (size_t)i * 8) = *(s16x8*)v;
}

// ---------------- init ----------------
__global__ void init_cnt(int* __restrict__ c) { c[threadIdx.x] = 0; }

// ---------------- gate: logits -> softmax -> top6 -> slot assign ----------------
__global__ __launch_bounds__(64) void gate_topk(
    const float* __restrict__ xg, const float* __restrict__ gw,
    int* __restrict__ cnt, int* __restrict__ tok_of,
    int* __restrict__ slot_enc, float* __restrict__ tw)
{
    const int t = blockIdx.x;
    const int lane = threadIdx.x;
    __shared__ float4 xs[512];
    const float4* xr = (const float4*)(xg + (size_t)t * H);
    #pragma unroll
    for (int i = 0; i < 8; ++i) xs[i * 64 + lane] = xr[i * 64 + lane];
    __syncthreads();

    const float4* gr = (const float4*)(gw + (size_t)lane * H);
    float acc = 0.f;
    #pragma unroll 4
    for (int i = 0; i < 512; ++i) {
        float4 a = xs[i], b = gr[i];
        acc += a.x * b.x + a.y * b.y + a.z * b.z + a.w * b.w;
    }
    float m = acc;
    #pragma unroll
    for (int off = 32; off; off >>= 1) m = fmaxf(m, __shfl_xor(m, off));
    float p = __expf(acc - m);
    float s = p;
    #pragma unroll
    for (int off = 32; off; off >>= 1) s += __shfl_xor(s, off);
    p = p / s;

    float myw = 0.f; int mye = 0;
    float v = p;
    for (int k = 0; k < 6; ++k) {
        float bv = v; int bi = lane;
        #pragma unroll
        for (int off = 32; off; off >>= 1) {
            float ov = __shfl_xor(bv, off);
            int   oi = __shfl_xor(bi, off);
            if (ov > bv || (ov == bv && oi < bi)) { bv = ov; bi = oi; }
        }
        if (lane == k)  { myw = bv; mye = bi; }
        if (lane == bi) v = -1.f;
    }
    if (lane < 6) {
        int slot = atomicAdd(&cnt[mye], 1);
        int enc = -1;
        if (slot < CAP) { tok_of[mye * CAP + slot] = t; enc = mye * CAP + slot; }
        slot_enc[t * 6 + lane] = enc;
        tw[t * 6 + lane] = myw;               // SCALE == 1.0
    }
}

// ---------------- fused gate+up grouped GEMM + SiLU ----------------
// BM=256, BN=64 per mat, BK=64. R2 skeleton: depth-1 reg prefetch,
// STORE -> BAR -> LOAD(kt+1) -> COMPUTE -> BAR (lgkm-only barriers).
template<bool ROUTED>
__global__ __launch_bounds__(256, 2) void dual_gemm(
    const u16* __restrict__ xbf, const int* __restrict__ tok_of,
    const int* __restrict__ cnt_arr, const float* __restrict__ wg,
    const float* __restrict__ wu, u16* __restrict__ act, int Fd)
{
    __shared__ u16 As[256 * 64];          // 32 KB
    __shared__ u16 Bgs[64 * 64];          // 8 KB
    __shared__ u16 Bus[64 * 64];          // 8 KB

    int e = 0, cnt, m0, f0;
    if constexpr (ROUTED) {
        e = blockIdx.z;
        cnt = cnt_arr[e]; cnt = cnt < CAP ? cnt : CAP;
        f0 = blockIdx.x * 64; m0 = blockIdx.y * 256;
        if (m0 >= cnt) return;
    } else {
        cnt = NTOK;
        m0 = blockIdx.x * 256; f0 = blockIdx.y * 64;
    }

    const float* wg_e = wg;
    const float* wu_e = wu;
    u16* act_e = act;
    if constexpr (ROUTED) {
        wg_e += (size_t)e * H * Fd;
        wu_e += (size_t)e * H * Fd;
        act_e += (size_t)e * CAP * Fd;
    }

    const int tid = threadIdx.x;
    const int lane = tid & 63;
    const int wv = tid >> 6;
    const int NT = H / 64;                // 32

    // ---- A geometry (R2): 8 lanes per row-chunk, coalesced 128B ----
    const int ac = tid & 7;
    int arl[8];
    const u16* arow[8];
    #pragma unroll
    for (int it = 0; it < 8; ++it) {
        int row = it * 32 + (tid >> 3);
        arl[it] = row;
        int srow = m0 + row;
        if constexpr (ROUTED) {
            const int* tok = tok_of + e * CAP;
            arow[it] = xbf + (size_t)tok[srow < cnt ? srow : 0] * H;
        } else {
            arow[it] = xbf + (size_t)srow * H;
        }
    }
    // ---- B geometry: 128 threads per mat ----
    const int mat = tid >> 7;
    const int bb = tid & 127;
    const float* bsrc;
    int bn4 = 0, bkq = 0, dr = 0, dh = 0;
    if constexpr (ROUTED) {
        bn4 = bb & 15; bkq = bb >> 4;              // 16x4=64 cols, 8 k-quad groups
        bsrc = (mat ? wu_e : wg_e) + (size_t)f0 + bn4 * 4;
    } else {
        dr = bb >> 1; dh = bb & 1;                 // 64 rows, 2 k-halves of 32
        bsrc = (mat ? wu_e : wg_e) + (size_t)(f0 + dr) * H + dh * 32;
    }

    f32x4 accg[4][4], accu[4][4];
    const f32x4 zero4 = {0.f, 0.f, 0.f, 0.f};
    #pragma unroll
    for (int i = 0; i < 4; ++i)
        #pragma unroll
        for (int j = 0; j < 4; ++j) { accg[i][j] = zero4; accu[i][j] = zero4; }

    s16x8 aR[8];
    f32x4 bR[8];

    auto LOAD = [&](int kt) {
        #pragma unroll
        for (int it = 0; it < 8; ++it)
            aR[it] = *(const s16x8*)(arow[it] + kt * 64 + ac * 8);
        if constexpr (ROUTED) {
            #pragma unroll
            for (int h = 0; h < 2; ++h) {
                int q16 = bkq + h * 8;            // k-quad index 0..15
                const float* s = bsrc + ((size_t)kt * 64 + q16 * 4) * Fd;
                #pragma unroll
                for (int j = 0; j < 4; ++j)
                    bR[h * 4 + j] = *(const f32x4*)(s + (size_t)j * Fd);
            }
        } else {
            #pragma unroll
            for (int q = 0; q < 8; ++q)
                bR[q] = *(const f32x4*)(bsrc + kt * 64 + q * 4);
        }
    };
    auto STORE = [&]() {
        #pragma unroll
        for (int it = 0; it < 8; ++it)
            *(s16x8*)&As[arl[it] * 64 + ((ac * 8) ^ swze(arl[it]))] = aR[it];
        u16* Bdst = mat ? Bus : Bgs;
        if constexpr (ROUTED) {
            #pragma unroll
            for (int h = 0; h < 2; ++h) {
                int q16 = bkq + h * 8;
                #pragma unroll
                for (int j = 0; j < 4; ++j) {
                    int rr = bn4 * 4 + j;
                    wr4(&Bdst[rr * 64 + ((q16 * 4) ^ swze(rr))],
                        bR[h * 4 + 0][j], bR[h * 4 + 1][j], bR[h * 4 + 2][j], bR[h * 4 + 3][j]);
                }
            }
        } else {
            #pragma unroll
            for (int q = 0; q < 8; ++q)
                wr4(&Bdst[dr * 64 + ((dh * 32 + q * 4) ^ swze(dr))],
                    bR[q].x, bR[q].y, bR[q].z, bR[q].w);
        }
    };
    auto COMPUTE = [&]() {
        __builtin_amdgcn_s_setprio(1);
        #pragma unroll
        for (int kk = 0; kk < 2; ++kk) {
            const int ko = kk * 32 + (lane >> 4) * 8;
            s16x8 a[4], bg[4], bu[4];
            #pragma unroll
            for (int mi = 0; mi < 4; ++mi) {
                int r = wv * 64 + mi * 16 + (lane & 15);
                a[mi] = *(const s16x8*)&As[r * 64 + (ko ^ swze(r))];
            }
            #pragma unroll
            for (int ni = 0; ni < 4; ++ni) {
                int r = ni * 16 + (lane & 15);
                bg[ni] = *(const s16x8*)&Bgs[r * 64 + (ko ^ swze(r))];
                bu[ni] = *(const s16x8*)&Bus[r * 64 + (ko ^ swze(r))];
            }
            #pragma unroll
            for (int mi = 0; mi < 4; ++mi)
                #pragma unroll
                for (int ni = 0; ni < 4; ++ni) {
                    accg[mi][ni] = __builtin_amdgcn_mfma_f32_16x16x32_bf16(a[mi], bg[ni], accg[mi][ni], 0, 0, 0);
                    accu[mi][ni] = __builtin_amdgcn_mfma_f32_16x16x32_bf16(a[mi], bu[ni], accu[mi][ni], 0, 0, 0);
                }
        }
        __builtin_amdgcn_s_setprio(0);
    };

    // ---- prologue ----
    LOAD(0);
    for (int kt = 0; kt < NT; ++kt) {
        STORE();                          // reg-dep waits tile kt's loads
        BAR(); SCHED_FENCE();             // publish LDS
        if (kt + 1 < NT) LOAD(kt + 1);    // issue next tile early
        SCHED_FENCE();
        COMPUTE();
        BAR(); SCHED_FENCE();             // readers done before next STORE
    }

    // ---- epilogue: silu(g)*u -> bf16 act (linear layout) ----
    #pragma unroll
    for (int mi = 0; mi < 4; ++mi)
        #pragma unroll
        for (int ni = 0; ni < 4; ++ni)
            #pragma unroll
            for (int r = 0; r < 4; ++r) {
                int srow = m0 + wv * 64 + mi * 16 + (lane >> 4) * 4 + r;
                if (srow < cnt) {
                    int fc = f0 + ni * 16 + (lane & 15);
                    float g = accg[mi][ni][r], u = accu[mi][ni][r];
                    float aa = (g / (1.f + __expf(-g))) * u;
                    act_e[(size_t)srow * Fd + fc] = f2bf(aa);
                }
            }
}

// ---------------- down-proj grouped GEMM ----------------
// BM=256, BN=128, BK=64. Same skeleton.
template<bool ROUTED>
__global__ __launch_bounds__(256, 2) void down_gemm(
    const u16* __restrict__ actA, const float* __restrict__ wdn,
    void* __restrict__ outp, const int* __restrict__ cnt_arr, int Kd)
{
    __shared__ u16 As[256 * 64];          // 32 KB
    __shared__ u16 Bs[128 * 64];          // 16 KB

    int e = 0, cnt, m0, n0;
    if constexpr (ROUTED) {
        e = blockIdx.z;
        cnt = cnt_arr[e]; cnt = cnt < CAP ? cnt : CAP;
        n0 = blockIdx.x * 128; m0 = blockIdx.y * 256;
        if (m0 >= cnt) return;
    } else {
        cnt = NTOK;
        m0 = blockIdx.x * 256; n0 = blockIdx.y * 128;
    }

    const u16* A_e = actA;
    const float* B_e = wdn;
    if constexpr (ROUTED) {
        A_e += (size_t)e * CAP * Kd;
        B_e += (size_t)e * Kd * H;
    }
    const int NT = Kd / 64;               // 22 or 44
    const int tid = threadIdx.x, lane = tid & 63, wv = tid >> 6;

    const int ac = tid & 7;
    int arl[8];
    const u16* arow[8];
    #pragma unroll
    for (int it = 0; it < 8; ++it) {
        int row = it * 32 + (tid >> 3);
        arl[it] = row;
        arow[it] = A_e + (size_t)(m0 + row) * Kd;
    }
    const float* bsrc;
    int bn4 = 0, bkq = 0, dr = 0, dh = 0;
    if constexpr (ROUTED) {
        bn4 = tid & 31; bkq = tid >> 5;            // 32x4=128 cols, 8 k-quad groups
        bsrc = B_e + (size_t)n0 + bn4 * 4;
    } else {
        dr = tid >> 1; dh = tid & 1;               // 128 rows, 2 k-halves
        bsrc = B_e + (size_t)(n0 + dr) * FSH + dh * 32;
    }

    f32x4 acc[4][8];
    const f32x4 zero4 = {0.f, 0.f, 0.f, 0.f};
    #pragma unroll
    for (int i = 0; i < 4; ++i)
        #pragma unroll
        for (int j = 0; j < 8; ++j) acc[i][j] = zero4;

    s16x8 aR[8];
    f32x4 bR[8];

    auto LOAD = [&](int kt) {
        #pragma unroll
        for (int it = 0; it < 8; ++it)
            aR[it] = *(const s16x8*)(arow[it] + kt * 64 + ac * 8);
        if constexpr (ROUTED) {
            #pragma unroll
            for (int h = 0; h < 2; ++h) {
                int q16 = bkq + h * 8;
                const float* s = bsrc + ((size_t)kt * 64 + q16 * 4) * H;
                #pragma unroll
                for (int j = 0; j < 4; ++j)
                    bR[h * 4 + j] = *(const f32x4*)(s + (size_t)j * H);
            }
        } else {
            #pragma unroll
            for (int q = 0; q < 8; ++q)
                bR[q] = *(const f32x4*)(bsrc + kt * 64 + q * 4);
        }
    };
    auto STORE = [&]() {
        #pragma unroll
        for (int it = 0; it < 8; ++it)
            *(s16x8*)&As[arl[it] * 64 + ((ac * 8) ^ swze(arl[it]))] = aR[it];
        if constexpr (ROUTED) {
            #pragma unroll
            for (int h = 0; h < 2; ++h) {
                int q16 = bkq + h * 8;
                #pragma unroll
                for (int j = 0; j < 4; ++j) {
                    int rr = bn4 * 4 + j;
                    wr4(&Bs[rr * 64 + ((q16 * 4) ^ swze(rr))],
                        bR[h * 4 + 0][j], bR[h * 4 + 1][j], bR[h * 4 + 2][j], bR[h * 4 + 3][j]);
                }
            }
        } else {
            #pragma unroll
            for (int q = 0; q < 8; ++q)
                wr4(&Bs[dr * 64 + ((dh * 32 + q * 4) ^ swze(dr))],
                    bR[q].x, bR[q].y, bR[q].z, bR[q].w);
        }
    };
    auto COMPUTE = [&]() {
        __builtin_amdgcn_s_setprio(1);
        #pragma unroll
        for (int kk = 0; kk < 2; ++kk) {
            const int ko = kk * 32 + (lane >> 4) * 8;
            s16x8 a[4], bf[8];
            #pragma unroll
            for (int mi = 0; mi < 4; ++mi) {
                int r = wv * 64 + mi * 16 + (lane & 15);
                a[mi] = *(const s16x8*)&As[r * 64 + (ko ^ swze(r))];
            }
            #pragma unroll
            for (int ni = 0; ni < 8; ++ni) {
                int r = ni * 16 + (lane & 15);
                bf[ni] = *(const s16x8*)&Bs[r * 64 + (ko ^ swze(r))];
            }
            #pragma unroll
            for (int mi = 0; mi < 4; ++mi)
                #pragma unroll
                for (int ni = 0; ni < 8; ++ni)
                    acc[mi][ni] = __builtin_amdgcn_mfma_f32_16x16x32_bf16(a[mi], bf[ni], acc[mi][ni], 0, 0, 0);
        }
        __builtin_amdgcn_s_setprio(0);
    };

    LOAD(0);
    for (int kt = 0; kt < NT; ++kt) {
        STORE();
        BAR(); SCHED_FENCE();
        if (kt + 1 < NT) LOAD(kt + 1);
        SCHED_FENCE();
        COMPUTE();
        BAR(); SCHED_FENCE();
    }

    #pragma unroll
    for (int mi = 0; mi < 4; ++mi)
        #pragma unroll
        for (int ni = 0; ni < 8; ++ni)
            #pragma unroll
            for (int r = 0; r < 4; ++r) {
                int srow = m0 + wv * 64 + mi * 16 + (lane >> 4) * 4 + r;
                if (srow < cnt) {
                    int col = n0 + ni * 16 + (lane & 15);
                    float vv = acc[mi][ni][r];
                    if constexpr (ROUTED)
                        ((u16*)outp)[(size_t)e * CAP * H + (size_t)srow * H + col] = f2bf(vv);
                    else
                        ((float*)outp)[(size_t)srow * H + col] = vv;
                }
            }
}

// ---------------- combine: y += sum_k w_k * d[enc_k] ----------------
__global__ __launch_bounds__(256) void combine(
    float* __restrict__ y, const u16* __restrict__ d,
    const int* __restrict__ slot_enc, const float* __restrict__ tw)
{
    const int t = blockIdx.x, tid = threadIdx.x;
    int enc[6]; float w[6];
    #pragma unroll
    for (int k = 0; k < 6; ++k) {
        enc[k] = slot_enc[t * 6 + k];
        w[k] = tw[t * 6 + k];
    }
    float4* yrow = (float4*)(y + (size_t)t * H);
    #pragma unroll
    for (int it = 0; it < 2; ++it) {
        int h4 = it * 256 + tid;
        float4 acc = yrow[h4];
        #pragma unroll
        for (int k = 0; k < 6; ++k) {
            if (enc[k] >= 0) {
                ushort4 dv = ((const ushort4*)(d + (size_t)enc[k] * H))[h4];
                acc.x += w[k] * bf2f(dv.x);
                acc.y += w[k] * bf2f(dv.y);
                acc.z += w[k] * bf2f(dv.z);
                acc.w += w[k] * bf2f(dv.w);
            }
        }
        yrow[h4] = acc;
    }
}

extern "C" void kernel_launch(void* const* d_in, const int* in_sizes, int n_in,
                              void* d_out, int out_size, void* d_ws, size_t ws_size,
                              hipStream_t stream) {
    const float* x       = (const float*)d_in[0];
    const float* gw      = (const float*)d_in[1];
    const float* w_gate  = (const float*)d_in[2];
    const float* w_up    = (const float*)d_in[3];
    const float* w_down  = (const float*)d_in[4];
    const float* sh_gate = (const float*)d_in[5];
    const float* sh_up   = (const float*)d_in[6];
    const float* sh_down = (const float*)d_in[7];
    float* y = (float*)d_out;

    char* wsb = (char*)d_ws;
    int*   cnt      = (int*)(wsb + 0);                       // 64 ints
    int*   tok_of   = (int*)(wsb + 512);                     // 64*512 ints
    int*   slot_enc = (int*)(wsb + 512 + 131072);            // 2048*6 ints
    float* tw       = (float*)(wsb + 512 + 131072 + 49152);  // 2048*6 floats
    u16*   act      = (u16*)(wsb + 230144);                  // 64*512*1408 bf16
    u16*   actsh    = (u16*)(wsb + 230144 + 92274688);       // 2048*2816 bf16
    u16*   dbuf     = (u16*)(wsb + 230144 + 92274688 + 11534336); // 64*512*2048 bf16
    u16*   xbf      = dbuf;  // alias: xbf (8MB) dead before down_gemm writes dbuf

    init_cnt<<<1, 64, 0, stream>>>(cnt);
    xcvt<<<NTOK * H / 8 / 256, 256, 0, stream>>>(x, xbf);
    gate_topk<<<NTOK, 64, 0, stream>>>(x, gw, cnt, tok_of, slot_enc, tw);
    dual_gemm<true><<<dim3(FDIM / 64, 2, NE), 256, 0, stream>>>(
        xbf, tok_of, cnt, w_gate, w_up, act, FDIM);
    dual_gemm<false><<<dim3(NTOK / 256, FSH / 64, 1), 256, 0, stream>>>(
        xbf, nullptr, nullptr, sh_gate, sh_up, actsh, FSH);
    down_gemm<true><<<dim3(H / 128, 2, NE), 256, 0, stream>>>(
        act, w_down, (void*)dbuf, cnt, FDIM);
    down_gemm<false><<<dim3(NTOK / 256, H / 128, 1), 256, 0, stream>>>(
        actsh, sh_down, (void*)y, nullptr, FSH);
    combine<<<NTOK, 256, 0, stream>>>(y, dbuf, slot_enc, tw);
}